// Round 6
// baseline (94.734 us; speedup 1.0000x reference)
//
#include <hip/hip_runtime.h>

#define NS 8192
#define MS 2048
#define DD 32
#define MSPLIT 16
#define NBLK (NS / 256)        // 32 n-groups
#define GRID (NBLK * MSPLIT)   // 512 blocks = 2/CU

typedef __attribute__((ext_vector_type(8))) short bf16x8;
typedef __attribute__((ext_vector_type(4))) float f32x4;
typedef unsigned short u16;

// ws floats: partial[MSPLIT][NS], then 1 uint counter
#define PART_FLOATS (MSPLIT * NS)
#define CNT_BYTE_OFF (PART_FLOATS * 4)

__device__ inline float fast_exp2(float x) {
#if __has_builtin(__builtin_amdgcn_exp2f)
    return __builtin_amdgcn_exp2f(x);
#else
    return exp2f(x);
#endif
}
__device__ inline float fast_rcp(float x) {
#if __has_builtin(__builtin_amdgcn_rcpf)
    return __builtin_amdgcn_rcpf(x);
#else
    return 1.0f / x;
#endif
}
__device__ inline u16 f2bf(float x) {  // round-to-nearest-even bf16
    unsigned u = __float_as_uint(x);
    return (u16)((u + 0x7fffu + ((u >> 16) & 1u)) >> 16);
}
__device__ inline float bf2f(u16 h) { return __uint_as_float(((unsigned)h) << 16); }

__device__ inline void split8(const float* v, bf16x8& hi, bf16x8& lo) {
#pragma unroll
    for (int j = 0; j < 8; ++j) {
        u16 h = f2bf(v[j]);
        hi[j] = (short)h;
        lo[j] = (short)f2bf(v[j] - bf2f(h));
    }
}

// One kernel: in-register fragment prep from raw fp32 inputs, 3-product
// bf16-split MFMA (hi*hi, lo*hi, hi*lo), exp2 epilogue, partial write,
// then last-block (atomic counter) global reduce + min/max + flip + out.
__global__ __launch_bounds__(256, 2) void kde_fused(const float* __restrict__ samples,
                                                    const float* __restrict__ means,
                                                    const float* __restrict__ stds,
                                                    float* __restrict__ ws,
                                                    float* __restrict__ out) {
    const int lane = threadIdx.x & 63, wid = threadIdx.x >> 6;
    const int r15 = lane & 15, g = lane >> 4;
    const int nb = blockIdx.x & (NBLK - 1);
    const int mb = blockIdx.x >> 5;            // 0..MSPLIT-1
    const int n_base = (nb * 4 + wid) * 64;
    const int m0 = mb * (MS / MSPLIT);         // 128 m per block
    const float L2E = 1.4426950408889634f;

    // ---- X fragments straight from samples (no staging) ----
    bf16x8 xh[4], xl[4], qh[4], ql[4];
#pragma unroll
    for (int nt = 0; nt < 4; ++nt) {
        const float* sp = samples + (size_t)(n_base + nt * 16 + r15) * DD + g * 8;
        float4 a = *(const float4*)sp, b = *(const float4*)(sp + 4);
        float xv[8] = {a.x, a.y, a.z, a.w, b.x, b.y, b.z, b.w};
        float qv[8];
#pragma unroll
        for (int j = 0; j < 8; ++j) qv[j] = xv[j] * xv[j];
        split8(xv, xh[nt], xl[nt]);
        split8(qv, qh[nt], ql[nt]);
    }

    f32x4 rs[4];
#pragma unroll
    for (int nt = 0; nt < 4; ++nt) rs[nt] = (f32x4){0.f, 0.f, 0.f, 0.f};

#pragma unroll 2
    for (int it = 0; it < 8; ++it) {
        const int mrow = m0 + it * 16 + r15;
        const float* mp = means + (size_t)mrow * DD + g * 8;
        const float* vp = stds + (size_t)mrow * DD + g * 8;
        float4 m1 = *(const float4*)mp, m2 = *(const float4*)(mp + 4);
        float4 s1 = *(const float4*)vp, s2 = *(const float4*)(vp + 4);
        float mu[8] = {m1.x, m1.y, m1.z, m1.w, m2.x, m2.y, m2.z, m2.w};
        float sd[8] = {s1.x, s1.y, s1.z, s1.w, s2.x, s2.y, s2.z, s2.w};
        float Bv[8], Cv[8];
        float ap = 0.f;
#pragma unroll
        for (int e = 0; e < 8; ++e) {
            float inv = fast_rcp(sd[e]);
            Bv[e] = L2E * mu[e] * inv;
            Cv[e] = -0.5f * L2E * inv;
            ap += mu[e] * mu[e] * inv;
        }
        bf16x8 bh, bl, ch, cl;
        split8(Bv, bh, bl);
        split8(Cv, ch, cl);
        // A2[mrow]: full-row sum lives across the 4 g-groups (lane bits 4,5)
        ap += __shfl_xor(ap, 16);
        ap += __shfl_xor(ap, 32);
        const float a2 = -0.5f * L2E * ap - 11.0f;  // -log2(M) folds the mean

#pragma unroll
        for (int nt = 0; nt < 4; ++nt) {
            f32x4 acc = (f32x4){0.f, 0.f, 0.f, 0.f};
            acc = __builtin_amdgcn_mfma_f32_16x16x32_bf16(xh[nt], bh, acc, 0, 0, 0);
            acc = __builtin_amdgcn_mfma_f32_16x16x32_bf16(qh[nt], ch, acc, 0, 0, 0);
            acc = __builtin_amdgcn_mfma_f32_16x16x32_bf16(xl[nt], bh, acc, 0, 0, 0);
            acc = __builtin_amdgcn_mfma_f32_16x16x32_bf16(ql[nt], ch, acc, 0, 0, 0);
            acc = __builtin_amdgcn_mfma_f32_16x16x32_bf16(xh[nt], bl, acc, 0, 0, 0);
            acc = __builtin_amdgcn_mfma_f32_16x16x32_bf16(qh[nt], cl, acc, 0, 0, 0);
#pragma unroll
            for (int r = 0; r < 4; ++r) rs[nt][r] += fast_exp2(acc[r] + a2);
        }
    }

    // reduce the 16 m-columns (lanes sharing g)
#pragma unroll
    for (int o = 1; o < 16; o <<= 1)
#pragma unroll
        for (int nt = 0; nt < 4; ++nt)
#pragma unroll
            for (int r = 0; r < 4; ++r) rs[nt][r] += __shfl_xor(rs[nt][r], o);

    float* partial = ws;
    if (r15 == 0) {
#pragma unroll
        for (int nt = 0; nt < 4; ++nt)
            *(f32x4*)(partial + (size_t)mb * NS + n_base + nt * 16 + g * 4) = rs[nt];
    }

    // ---- completion detection; last block does the global tail ----
    __threadfence();
    __shared__ int lastFlag;
    if (threadIdx.x == 0) {
        unsigned old = atomicAdd((unsigned*)((char*)ws + CNT_BYTE_OFF), 1u);
        lastFlag = (old == GRID - 1);
    }
    __syncthreads();
    if (!lastFlag) return;
    __threadfence();  // acquire all blocks' partial writes

    const int t = threadIdx.x;
    f32x4 acc4[8];
#pragma unroll
    for (int c = 0; c < 8; ++c) acc4[c] = (f32x4){0.f, 0.f, 0.f, 0.f};
    for (int j = 0; j < MSPLIT; ++j) {
        const float* row = partial + (size_t)j * NS;
#pragma unroll
        for (int c = 0; c < 8; ++c)
            acc4[c] += *(const f32x4*)(row + c * 1024 + t * 4);
    }

    float mn = acc4[0][0], mx = acc4[0][0];
#pragma unroll
    for (int c = 0; c < 8; ++c)
#pragma unroll
        for (int r = 0; r < 4; ++r) {
            mn = fminf(mn, acc4[c][r]);
            mx = fmaxf(mx, acc4[c][r]);
        }
#pragma unroll
    for (int o = 1; o < 64; o <<= 1) {
        mn = fminf(mn, __shfl_xor(mn, o));
        mx = fmaxf(mx, __shfl_xor(mx, o));
    }
    __shared__ float smn[4], smx[4];
    if ((t & 63) == 0) { smn[t >> 6] = mn; smx[t >> 6] = mx; }
    __syncthreads();
    const float fmn = fminf(fminf(smn[0], smn[1]), fminf(smn[2], smn[3]));
    const float fmx = fmaxf(fmaxf(smx[0], smx[1]), fmaxf(smx[2], smx[3]));

#pragma unroll
    for (int c = 0; c < 8; ++c) {
        f32x4 o4;
#pragma unroll
        for (int r = 0; r < 4; ++r) o4[r] = fmx + fmn - acc4[c][r];
        *(f32x4*)(out + c * 1024 + t * 4) = o4;
    }
}

extern "C" void kernel_launch(void* const* d_in, const int* in_sizes, int n_in,
                              void* d_out, int out_size, void* d_ws, size_t ws_size,
                              hipStream_t stream) {
    const float* samples = (const float*)d_in[0];
    const float* means   = (const float*)d_in[1];
    const float* stds    = (const float*)d_in[2];
    float* ws  = (float*)d_ws;
    float* out = (float*)d_out;

    // counter must be 0 every call (ws is poisoned 0xAA once, never restored)
    hipMemsetAsync((char*)d_ws + CNT_BYTE_OFF, 0, 4, stream);
    kde_fused<<<dim3(GRID), 256, 0, stream>>>(samples, means, stds, ws, out);
}

// Round 7
// 52.910 us; speedup vs baseline: 1.7905x; 1.7905x over previous
//
#include <hip/hip_runtime.h>

#define NS 8192
#define MS 2048
#define DD 32
#define MSPLIT 8
#define MCH (MS / MSPLIT)   // 256 m per block
#define NITS (MCH / 16)     // 16 m-tiles per block

typedef __attribute__((ext_vector_type(8))) short bf16x8;
typedef __attribute__((ext_vector_type(4))) float f32x4;
typedef unsigned short u16;

// ---- ws byte offsets (round-5 layout, PART oversized is fine) ----
#define WH_OFF   (0)                        // [M][64] bf16 hi
#define WL_OFF   (256*1024)                 // [M][64] bf16 lo
#define XH_OFF   (512*1024)                 // [N][32] s  hi
#define XL_OFF   (1024*1024)                // [N][32] s  lo
#define QH_OFF   (1536*1024)                // [N][32] s^2 hi
#define QL_OFF   (2048*1024)                // [N][32] s^2 lo
#define A2_OFF   (2560*1024)                // [M] f32
#define PART_OFF (A2_OFF + 8*1024)          // [MSPLIT][N] f32
#define DIST_OFF (PART_OFF + 32*NS*4)
#define MM_OFF   (DIST_OFF + NS*4)          // 2 u32 (min,max bits)
#define CNT_OFF  (MM_OFF + 8)               // 1 u32

__device__ inline float fast_exp2(float x) {
#if __has_builtin(__builtin_amdgcn_exp2f)
    return __builtin_amdgcn_exp2f(x);
#else
    return exp2f(x);
#endif
}
__device__ inline u16 f2bf(float x) {  // round-to-nearest-even bf16
    unsigned u = __float_as_uint(x);
    return (u16)((u + 0x7fffu + ((u >> 16) & 1u)) >> 16);
}
__device__ inline float bf2f(u16 h) { return __uint_as_float(((unsigned)h) << 16); }

// prep (round-5, proven): balanced W path (64 blocks) + X path (256 blocks).
__global__ __launch_bounds__(256) void prep_kernel(const float* __restrict__ samples,
                                                   const float* __restrict__ means,
                                                   const float* __restrict__ stds,
                                                   unsigned char* __restrict__ ws) {
    const int tid = threadIdx.x, bid = blockIdx.x;
    if (bid == 0 && tid == 0) {
        unsigned* mm = (unsigned*)(ws + MM_OFF);
        mm[0] = 0x7f7fffffu;  // FLT_MAX bits
        mm[1] = 0u;
        *(unsigned*)(ws + CNT_OFF) = 0u;
    }
    if (bid < 64) {
        const int p = bid * 256 + tid;        // < 16384
        const int m = p >> 3;
        const int c = p & 7;                  // c<4 -> B rows, c>=4 -> C rows
        const int d0 = (c & 3) * 8;
        const bool isB = (c < 4);

        const float4* mrow = (const float4*)(means + (size_t)m * DD + d0);
        const float4* srow = (const float4*)(stds  + (size_t)m * DD + d0);
        float4 mu4a = mrow[0], mu4b = mrow[1];
        float4 sd4a = srow[0], sd4b = srow[1];
        float mu[8] = {mu4a.x, mu4a.y, mu4a.z, mu4a.w, mu4b.x, mu4b.y, mu4b.z, mu4b.w};
        float sd[8] = {sd4a.x, sd4a.y, sd4a.z, sd4a.w, sd4b.x, sd4b.y, sd4b.z, sd4b.w};

        const float L2E = 1.4426950408889634f;
        float a = 0.f;
        ushort4 h0, h1, l0, l1;
        u16* ph = (u16*)&h0; u16* ph1 = (u16*)&h1;
        u16* pl = (u16*)&l0; u16* pl1 = (u16*)&l1;
#pragma unroll
        for (int e = 0; e < 8; ++e) {
            float inv = 1.0f / sd[e];
            float val = isB ? (L2E * mu[e] * inv) : (-0.5f * L2E * inv);
            if (isB) a += mu[e] * mu[e] * inv;
            u16 h = f2bf(val);
            u16 l = f2bf(val - bf2f(h));
            if (e < 4) { ph[e] = h; pl[e] = l; }
            else       { ph1[e - 4] = h; pl1[e - 4] = l; }
        }
        a += __shfl_xor(a, 1);
        a += __shfl_xor(a, 2);
        a += __shfl_xor(a, 4);
        if (c == 0) ((float*)(ws + A2_OFF))[m] = -0.5f * L2E * a - 11.0f;

        u16* WH = (u16*)(ws + WH_OFF) + (size_t)m * 64 + c * 8;
        u16* WL = (u16*)(ws + WL_OFF) + (size_t)m * 64 + c * 8;
        *(ushort4*)(WH)     = h0;
        *(ushort4*)(WH + 4) = h1;
        *(ushort4*)(WL)     = l0;
        *(ushort4*)(WL + 4) = l1;
    } else {
        const int idx = (bid - 64) * 256 + tid;  // < NS*DD/4
        float4 v = ((const float4*)samples)[idx];
        float xs[4] = {v.x, v.y, v.z, v.w};
        ushort4 hx, lx, hq, lq;
        u16* ph = (u16*)&hx; u16* pl = (u16*)&lx;
        u16* qh = (u16*)&hq; u16* ql = (u16*)&lq;
#pragma unroll
        for (int j = 0; j < 4; ++j) {
            float x = xs[j];
            u16 h = f2bf(x);
            ph[j] = h;
            pl[j] = f2bf(x - bf2f(h));
            float q = x * x;
            u16 hh = f2bf(q);
            qh[j] = hh;
            ql[j] = f2bf(q - bf2f(hh));
        }
        *(ushort4*)((u16*)(ws + XH_OFF) + idx * 4) = hx;
        *(ushort4*)((u16*)(ws + XL_OFF) + idx * 4) = lx;
        *(ushort4*)((u16*)(ws + QH_OFF) + idx * 4) = hq;
        *(ushort4*)((u16*)(ws + QL_OFF) + idx * 4) = lq;
    }
}

// Lean main: ONE 16-row n-tile per wave so the whole live set (~57 VGPR:
// X frags 16 + rs 4 + W frags 16 + acc/a2/addr) fits even a 64-VGPR
// allocation — round 6 proved the allocator targets 64 and spills anything
// bigger (VGPR_Count=64, VALUBusy 8%, 91 us). No fences here.
__global__ __launch_bounds__(256, 4) void kde_mfma2(const unsigned char* __restrict__ ws,
                                                    float* __restrict__ partial) {
    const u16* XH = (const u16*)(ws + XH_OFF);
    const u16* XL = (const u16*)(ws + XL_OFF);
    const u16* QH = (const u16*)(ws + QH_OFF);
    const u16* QL = (const u16*)(ws + QL_OFF);
    const u16* WH = (const u16*)(ws + WH_OFF);
    const u16* WL = (const u16*)(ws + WL_OFF);
    const float* A2 = (const float*)(ws + A2_OFF);

    const int lane = threadIdx.x & 63, wid = threadIdx.x >> 6;
    const int r15 = lane & 15, g = lane >> 4;
    const int n0 = (blockIdx.x * 4 + wid) * 16;
    const int m0 = blockIdx.y * MCH;

    const size_t xoff = (size_t)(n0 + r15) * DD + g * 8;
    bf16x8 xh = *(const bf16x8*)(XH + xoff);
    bf16x8 xl = *(const bf16x8*)(XL + xoff);
    bf16x8 qh = *(const bf16x8*)(QH + xoff);
    bf16x8 ql = *(const bf16x8*)(QL + xoff);

    f32x4 rs = (f32x4){0.f, 0.f, 0.f, 0.f};

#pragma unroll 2
    for (int it = 0; it < NITS; ++it) {
        const int mrow = m0 + it * 16 + r15;
        const size_t woff = (size_t)mrow * 64 + g * 8;
        bf16x8 bh = *(const bf16x8*)(WH + woff);
        bf16x8 ch = *(const bf16x8*)(WH + woff + 32);
        bf16x8 bl = *(const bf16x8*)(WL + woff);
        bf16x8 cl = *(const bf16x8*)(WL + woff + 32);
        const float a2 = A2[mrow];

        f32x4 acc = (f32x4){0.f, 0.f, 0.f, 0.f};
        acc = __builtin_amdgcn_mfma_f32_16x16x32_bf16(xh, bh, acc, 0, 0, 0);
        acc = __builtin_amdgcn_mfma_f32_16x16x32_bf16(qh, ch, acc, 0, 0, 0);
        acc = __builtin_amdgcn_mfma_f32_16x16x32_bf16(xl, bh, acc, 0, 0, 0);
        acc = __builtin_amdgcn_mfma_f32_16x16x32_bf16(ql, ch, acc, 0, 0, 0);
        acc = __builtin_amdgcn_mfma_f32_16x16x32_bf16(xh, bl, acc, 0, 0, 0);
        acc = __builtin_amdgcn_mfma_f32_16x16x32_bf16(qh, cl, acc, 0, 0, 0);
#pragma unroll
        for (int r = 0; r < 4; ++r) rs[r] += fast_exp2(acc[r] + a2);
    }

    // sum the 16 m-columns (lanes sharing g)
#pragma unroll
    for (int o = 1; o < 16; o <<= 1)
#pragma unroll
        for (int r = 0; r < 4; ++r) rs[r] += __shfl_xor(rs[r], o);

    if (r15 == 0)
        *(f32x4*)(partial + (size_t)blockIdx.y * NS + n0 + g * 4) = rs;
}

// Sum partials -> dist, block min/max -> atomics; last block finalizes out.
__global__ __launch_bounds__(256) void reduce_final(unsigned char* __restrict__ ws,
                                                    float* __restrict__ out) {
    const float* partial = (const float*)(ws + PART_OFF);
    float* dist = (float*)(ws + DIST_OFF);
    unsigned* mm = (unsigned*)(ws + MM_OFF);
    unsigned* cnt = (unsigned*)(ws + CNT_OFF);

    const int tid = threadIdx.x;
    const int n = blockIdx.x * 256 + tid;
    float v = 0.f;
#pragma unroll
    for (int j = 0; j < MSPLIT; ++j) v += partial[(size_t)j * NS + n];
    dist[n] = v;

    float mn = v, mx = v;
#pragma unroll
    for (int o = 1; o < 64; o <<= 1) {
        mn = fminf(mn, __shfl_xor(mn, o));
        mx = fmaxf(mx, __shfl_xor(mx, o));
    }
    __shared__ float smn[4], smx[4];
    __shared__ int lastFlag;
    const int wv = tid >> 6, ln = tid & 63;
    if (ln == 0) { smn[wv] = mn; smx[wv] = mx; }
    __syncthreads();
    if (tid == 0) {
#pragma unroll
        for (int j = 1; j < 4; ++j) {
            mn = fminf(mn, smn[j]);
            mx = fmaxf(mx, smx[j]);
        }
        atomicMin(mm + 0, __float_as_uint(mn));
        atomicMax(mm + 1, __float_as_uint(mx));
        __threadfence();
        unsigned old = atomicAdd(cnt, 1u);
        lastFlag = (old == (unsigned)(gridDim.x - 1));
    }
    __syncthreads();
    if (lastFlag) {
        __threadfence();
        volatile unsigned* vmm = mm;
        const float fmn = __uint_as_float(vmm[0]);
        const float fmx = __uint_as_float(vmm[1]);
        volatile float* vd = dist;
        for (int i = tid; i < NS; i += 256) out[i] = fmx + fmn - vd[i];
    }
}

extern "C" void kernel_launch(void* const* d_in, const int* in_sizes, int n_in,
                              void* d_out, int out_size, void* d_ws, size_t ws_size,
                              hipStream_t stream) {
    const float* samples = (const float*)d_in[0];
    const float* means   = (const float*)d_in[1];
    const float* stds    = (const float*)d_in[2];
    unsigned char* ws = (unsigned char*)d_ws;
    float* out = (float*)d_out;

    prep_kernel<<<dim3(64 + NS * DD / 4 / 256), 256, 0, stream>>>(samples, means, stds, ws);
    kde_mfma2<<<dim3(NS / 64, MSPLIT), 256, 0, stream>>>(ws, (float*)(ws + PART_OFF));
    reduce_final<<<dim3(NS / 256), 256, 0, stream>>>(ws, out);
}